// Round 3
// baseline (678.141 us; speedup 1.0000x reference)
//
#include <hip/hip_runtime.h>
#include <stdint.h>

#define BB    2
#define NN    1280
#define KK    48
#define CN    384
#define CE    128
#define CB    192
#define HID   512
#define CO    128
#define MM    (BB*NN*KK)   /* 122880 */
#define CH    (MM/2)       /* chunk rows: 61440 = exactly one batch b */

typedef __bf16 bf16x8 __attribute__((ext_vector_type(8)));
typedef float  f32x4  __attribute__((ext_vector_type(4)));
typedef unsigned short u16x8 __attribute__((ext_vector_type(8)));

__device__ __forceinline__ unsigned short f2bf(float f) {
  unsigned int i = __builtin_bit_cast(unsigned int, f);
  unsigned int r = (i + 0x7fffu + ((i >> 16) & 1u)) >> 16;
  return (unsigned short)r;
}
__device__ __forceinline__ float bf2f(unsigned short u) {
  unsigned int v = ((unsigned int)u) << 16;
  return __builtin_bit_cast(float, v);
}

// async global->LDS, 16B/lane; LDS dest is wave-uniform base + lane*16.
__device__ __forceinline__ void gload_lds16(const void* g, void* l) {
  __builtin_amdgcn_global_load_lds(
      (const __attribute__((address_space(1))) void*)g,
      (__attribute__((address_space(3))) void*)l, 16, 0, 0);
}

// ---------------- transpose+cast: out_bf16[C][R] = in_f32[R][C] ----------------
__global__ void k_transpose_cast(const float* __restrict__ in,
                                 unsigned short* __restrict__ out,
                                 int R, int C) {
  __shared__ float tile[32][33];
  const int c0 = blockIdx.x * 32, r0 = blockIdx.y * 32;
  const int tx = threadIdx.x, ty = threadIdx.y;
#pragma unroll
  for (int dy = 0; dy < 32; dy += 8)
    tile[ty + dy][tx] = in[(size_t)(r0 + ty + dy) * C + c0 + tx];
  __syncthreads();
#pragma unroll
  for (int dy = 0; dy < 32; dy += 8)
    out[(size_t)(c0 + ty + dy) * R + r0 + tx] = f2bf(tile[tx][ty + dy]);
}

// ---------------- node embed: n = node_emb @ Wi + bi ----------------
__global__ void k_node(const float* __restrict__ node,
                       const float* __restrict__ Wi,
                       const float* __restrict__ bi,
                       unsigned short* __restrict__ nbuf) {
  __shared__ float row[CN];
  const int blk = blockIdx.x;
  const float* src = node + (size_t)blk * CN;
  for (int c = threadIdx.x; c < CN; c += CB) row[c] = src[c];
  __syncthreads();
  const int t = threadIdx.x;
  float acc = bi[t];
#pragma unroll 8
  for (int c = 0; c < CN; ++c) acc += row[c] * Wi[(size_t)c * CB + t];
  nbuf[(size_t)blk * CB + t] = f2bf(acc);
}

// =======================================================================
// Streaming GEMM structure: per block, (1) burst-issue the wave's ENTIRE
// A panel into registers (K=512 fits), (2) load the B panel (64 n-cols x
// 512 K, XOR-swizzled) into LDS once, (3) one __syncthreads, (4) barrier-
// free fully-unrolled K loop of ds_read+MFMA, (5) epilogue reusing B LDS.
// B LDS layout: [8 windows][64 rows][8 chunks x16B], phys chunk = logical
// ^ (row&7); staged via pre-swizzled global source, linear LDS dest.
// =======================================================================

// ---------------- GEMM1: h1 = relu(x @ W1 + b1), x gathered to registers ----
__global__ __launch_bounds__(256, 2)
void k_gemm1(const float* __restrict__ edge,
             const unsigned short* __restrict__ nbuf,
             const int* __restrict__ eidx,
             const unsigned short* __restrict__ Wt,   // [512][512] = W1^T bf16
             const float* __restrict__ bias,
             unsigned short* __restrict__ out,        // h1 chunk [CH][512]
             int mbase, int b) {
  __shared__ char lds[65536];
  const int flat = blockIdx.x;                 // 7680 blocks
  const int xcd = flat & 7;
  const int p = flat >> 3;
  const int m0 = (xcd * 120 + (p >> 3)) * 64;  // 8 n-tiles of an m-panel stay on one XCD
  const int n0 = (p & 7) * 64;
  const int tid = threadIdx.x;
  const int l = tid & 63;
  const int w = tid >> 6;
  const int sr = l >> 3, pc = l & 7;
  const int kg = l >> 4, lr = l & 15;

  // ---- A: burst-issue the wave's 16 rows, all K, to registers ----
  // x[m] = [edge f32 (k<128) | nbuf[m/48] (128..320) | nbuf[b*N+eidx] (320..512)]
  const int m = mbase + m0 + w * 16 + lr;
  const int big = m / KK;
  const int nbr = b * NN + eidx[m];
  const float* ep = edge + (size_t)m * CE + kg * 8;
  float4 ed0[4], ed1[4];
#pragma unroll
  for (int s = 0; s < 4; ++s) {
    ed0[s] = *(const float4*)(ep + s * 32);
    ed1[s] = *(const float4*)(ep + s * 32 + 4);
  }
  const unsigned short* sp = nbuf + (size_t)big * CB + kg * 8;
  const unsigned short* np = nbuf + (size_t)nbr * CB + kg * 8;
  bf16x8 sf[6], nb[6];
#pragma unroll
  for (int s = 0; s < 6; ++s) sf[s] = *(const bf16x8*)(sp + s * 32);
#pragma unroll
  for (int s = 0; s < 6; ++s) nb[s] = *(const bf16x8*)(np + s * 32);

  // ---- B: stage Wt rows n0..n0+63, full K, into LDS (once) ----
#pragma unroll
  for (int ww = 0; ww < 2; ++ww) {
    const int win = w * 2 + ww;
#pragma unroll
    for (int j = 0; j < 8; ++j)
      gload_lds16(Wt + (size_t)(n0 + j * 8 + sr) * HID + win * 64 + (pc ^ sr) * 8,
                  lds + win * 8192 + j * 1024);
  }
  __syncthreads();   // drains all vmem: A in regs, B in LDS

  f32x4 acc[4];
#pragma unroll
  for (int nt = 0; nt < 4; ++nt) acc[nt] = (f32x4){0.f, 0.f, 0.f, 0.f};

#pragma unroll
  for (int s = 0; s < 16; ++s) {               // K-32 steps, barrier-free
    bf16x8 av;
    if (s < 4) {
      u16x8 pk;
      pk[0] = f2bf(ed0[s].x); pk[1] = f2bf(ed0[s].y);
      pk[2] = f2bf(ed0[s].z); pk[3] = f2bf(ed0[s].w);
      pk[4] = f2bf(ed1[s].x); pk[5] = f2bf(ed1[s].y);
      pk[6] = f2bf(ed1[s].z); pk[7] = f2bf(ed1[s].w);
      av = __builtin_bit_cast(bf16x8, pk);
    } else if (s < 10) {
      av = sf[s - 4];
    } else {
      av = nb[s - 10];
    }
    const char* bwin = lds + (s >> 1) * 8192;
    const int kk = s & 1;
#pragma unroll
    for (int nt = 0; nt < 4; ++nt) {
      const int rb = nt * 16 + lr;
      const bf16x8 bv = *(const bf16x8*)(bwin + rb * 128 + (((kk << 2) + kg) ^ (rb & 7)) * 16);
      acc[nt] = __builtin_amdgcn_mfma_f32_16x16x32_bf16(av, bv, acc[nt], 0, 0, 0);
    }
  }

  // ---- epilogue: bias+relu -> LDS tile (reuses B space) -> coalesced stores ----
  __syncthreads();                       // all waves done reading B
  unsigned short* tile = (unsigned short*)lds;   // [64][64] bf16, chunk-swizzled
#pragma unroll
  for (int nt = 0; nt < 4; ++nt) {
    const int col = nt * 16 + lr;
    const float bvv = bias[n0 + col];
    const int cn = col >> 3, cb = col & 7;
#pragma unroll
    for (int r = 0; r < 4; ++r) {
      float v = acc[nt][r] + bvv;
      v = v > 0.f ? v : 0.f;
      const int row = w * 16 + kg * 4 + r;
      tile[row * 64 + ((cn ^ (row & 7)) << 3) + cb] = f2bf(v);
    }
  }
  __syncthreads();
#pragma unroll
  for (int i = 0; i < 2; ++i) {
    const int c = i * 256 + tid;
    const int row = c >> 3, cn = c & 7;
    u16x8 vv = *(const u16x8*)(tile + row * 64 + ((cn ^ (row & 7)) << 3));
    *(u16x8*)(out + (size_t)(m0 + row) * HID + n0 + cn * 8) = vv;
  }
}

// ---------------- GEMM2: a = relu(h1 @ W2 + b2) + x ----------------
__global__ __launch_bounds__(256, 2)
void k_gemm2(const unsigned short* __restrict__ A,    // h1 chunk
             const unsigned short* __restrict__ Wt,   // W2^T bf16
             const float* __restrict__ bias,
             const float* __restrict__ edge,
             const unsigned short* __restrict__ nbuf,
             const int* __restrict__ eidx,
             unsigned short* __restrict__ out,        // abuf chunk
             int mbase, int b) {
  __shared__ char lds[65536];
  const int flat = blockIdx.x;                 // 3840 blocks
  const int xcd = flat & 7;
  const int p = flat >> 3;
  const int m0 = (xcd * 60 + (p >> 3)) * 128;
  const int n0 = (p & 7) * 64;
  const int tid = threadIdx.x;
  const int l = tid & 63;
  const int w = tid >> 6;
  const int sr = l >> 3, pc = l & 7;
  const int kg = l >> 4, lr = l & 15;

  // ---- A: burst-issue the wave's 32 rows, all K (128 VGPR) ----
  bf16x8 areg[2][16];
#pragma unroll
  for (int t = 0; t < 2; ++t) {
    const unsigned short* ap = A + (size_t)(m0 + w * 32 + t * 16 + lr) * HID + kg * 8;
#pragma unroll
    for (int s = 0; s < 16; ++s) areg[t][s] = *(const bf16x8*)(ap + s * 32);
  }
  // ---- B: stage Wt rows n0..n0+63 into LDS (once) ----
#pragma unroll
  for (int ww = 0; ww < 2; ++ww) {
    const int win = w * 2 + ww;
#pragma unroll
    for (int j = 0; j < 8; ++j)
      gload_lds16(Wt + (size_t)(n0 + j * 8 + sr) * HID + win * 64 + (pc ^ sr) * 8,
                  lds + win * 8192 + j * 1024);
  }
  __syncthreads();

  f32x4 acc[2][4];
#pragma unroll
  for (int t = 0; t < 2; ++t)
#pragma unroll
    for (int nt = 0; nt < 4; ++nt) acc[t][nt] = (f32x4){0.f, 0.f, 0.f, 0.f};

#pragma unroll
  for (int s = 0; s < 16; ++s) {               // barrier-free K loop
    const char* bwin = lds + (s >> 1) * 8192;
    const int kk = s & 1;
    bf16x8 bv[4];
#pragma unroll
    for (int nt = 0; nt < 4; ++nt) {
      const int rb = nt * 16 + lr;
      bv[nt] = *(const bf16x8*)(bwin + rb * 128 + (((kk << 2) + kg) ^ (rb & 7)) * 16);
    }
#pragma unroll
    for (int t = 0; t < 2; ++t)
#pragma unroll
      for (int nt = 0; nt < 4; ++nt)
        acc[t][nt] = __builtin_amdgcn_mfma_f32_16x16x32_bf16(areg[t][s], bv[nt], acc[t][nt], 0, 0, 0);
  }

  // ---- epilogue: bias+relu -> LDS tile; store with residual re-gather ----
  __syncthreads();
  unsigned short* tile = (unsigned short*)lds;   // [128][64] bf16
#pragma unroll
  for (int t = 0; t < 2; ++t)
#pragma unroll
    for (int nt = 0; nt < 4; ++nt) {
      const int col = nt * 16 + lr;
      const float bvv = bias[n0 + col];
      const int cn = col >> 3, cb = col & 7;
#pragma unroll
      for (int r = 0; r < 4; ++r) {
        float v = acc[t][nt][r] + bvv;
        v = v > 0.f ? v : 0.f;
        const int row = w * 32 + t * 16 + kg * 4 + r;
        tile[row * 64 + ((cn ^ (row & 7)) << 3) + cb] = f2bf(v);
      }
    }
  __syncthreads();
#pragma unroll
  for (int i = 0; i < 4; ++i) {
    const int c = i * 256 + tid;
    const int row = c >> 3, cn = c & 7;
    u16x8 vv = *(const u16x8*)(tile + row * 64 + ((cn ^ (row & 7)) << 3));
    const int mm = mbase + m0 + row;
    float rv[8];
    if (n0 < 128) {                      // edge cols (f32)
      const float4* rp = (const float4*)(edge + (size_t)mm * CE + n0 + cn * 8);
      float4 x0 = rp[0], x1 = rp[1];
      rv[0] = x0.x; rv[1] = x0.y; rv[2] = x0.z; rv[3] = x0.w;
      rv[4] = x1.x; rv[5] = x1.y; rv[6] = x1.z; rv[7] = x1.w;
    } else if (n0 < 320) {               // self cols 128..319
      u16x8 xv = *(const u16x8*)(nbuf + (size_t)(mm / KK) * CB + (n0 - 128) + cn * 8);
#pragma unroll
      for (int j = 0; j < 8; ++j) rv[j] = bf2f(xv[j]);
    } else {                             // nbr cols 320..511
      u16x8 xv = *(const u16x8*)(nbuf + (size_t)(b * NN + eidx[mm]) * CB + (n0 - 320) + cn * 8);
#pragma unroll
      for (int j = 0; j < 8; ++j) rv[j] = bf2f(xv[j]);
    }
#pragma unroll
    for (int j = 0; j < 8; ++j) vv[j] = f2bf(bf2f(vv[j]) + rv[j]);
    *(u16x8*)(out + (size_t)(m0 + row) * HID + n0 + cn * 8) = vv;
  }
}

// ---------------- final GEMM + LayerNorm (LDS-free; Wft streamed from L2) ----
__global__ __launch_bounds__(256, 2)
void k_final(const unsigned short* __restrict__ A,     // abuf chunk [CH][512]
             const unsigned short* __restrict__ Wft,   // [128][512] = Wf^T bf16
             const float* __restrict__ bias,
             const float* __restrict__ gamma,
             const float* __restrict__ beta,
             float* __restrict__ out) {
  const int flat = blockIdx.x;                 // 960 blocks
  const int xcd = flat & 7;
  const int p = flat >> 3;                     // 0..119
  const int m0 = (xcd * 120 + p) * 64;
  const int tid = threadIdx.x;
  const int l = tid & 63;
  const int w = tid >> 6;
  const int kg = l >> 4, lr = l & 15;

  // A: the wave's 16 rows, all K, burst to registers (64 VGPR)
  bf16x8 areg[16];
  const unsigned short* ap = A + (size_t)(m0 + w * 16 + lr) * HID + kg * 8;
#pragma unroll
  for (int s = 0; s < 16; ++s) areg[s] = *(const bf16x8*)(ap + s * 32);

  f32x4 acc[8];
#pragma unroll
  for (int j = 0; j < 8; ++j) acc[j] = (f32x4){0.f, 0.f, 0.f, 0.f};

#pragma unroll
  for (int s = 0; s < 16; ++s) {
#pragma unroll
    for (int nt = 0; nt < 8; ++nt) {
      const bf16x8 bv = *(const bf16x8*)(Wft + (size_t)(nt * 16 + lr) * HID + s * 32 + kg * 8);
      acc[nt] = __builtin_amdgcn_mfma_f32_16x16x32_bf16(areg[s], bv, acc[nt], 0, 0, 0);
    }
  }

  float gg[8], bb[8], bs[8];
#pragma unroll
  for (int j = 0; j < 8; ++j) {
    const int col = j * 16 + lr;
    gg[j] = gamma[col];
    bb[j] = beta[col];
    bs[j] = bias[col];
  }
#pragma unroll
  for (int r = 0; r < 4; ++r) {
    float s = 0.f, ss = 0.f;
#pragma unroll
    for (int j = 0; j < 8; ++j) {
      const float v = acc[j][r] + bs[j];
      acc[j][r] = v;
      s += v;
      ss += v * v;
    }
#pragma unroll
    for (int mk = 1; mk < 16; mk <<= 1) {
      s  += __shfl_xor(s, mk, 64);
      ss += __shfl_xor(ss, mk, 64);
    }
    const float mu = s * (1.f / 128.f);
    const float var = ss * (1.f / 128.f) - mu * mu;
    const float rstd = rsqrtf(var + 1e-5f);
    const int row = m0 + w * 16 + kg * 4 + r;
#pragma unroll
    for (int j = 0; j < 8; ++j) {
      const float v = (acc[j][r] - mu) * rstd * gg[j] + bb[j];
      out[(size_t)row * CO + j * 16 + lr] = v;
    }
  }
}

// ---------------- workspace layout (bytes) ----------------
// nbuf 983K | Wt1 512K | Wt2 512K | Wft 128K | h1 chunk 63M | abuf chunk 63M
#define O_N    ((size_t)0)
#define O_WT1  ((size_t)0x100000)
#define O_WT2  (O_WT1 + (size_t)0x80000)
#define O_WFT  (O_WT2 + (size_t)0x80000)
#define O_H1   ((size_t)0x300000)
#define O_A    (O_H1 + (size_t)CH * HID * 2)

extern "C" void kernel_launch(void* const* d_in, const int* in_sizes, int n_in,
                              void* d_out, int out_size, void* d_ws, size_t ws_size,
                              hipStream_t stream) {
  const float* node  = (const float*)d_in[0];
  const float* edge  = (const float*)d_in[1];
  const int*   eidx  = (const int*)d_in[2];
  const float* Wi    = (const float*)d_in[3];
  const float* bi    = (const float*)d_in[4];
  const float* W1    = (const float*)d_in[5];
  const float* b1    = (const float*)d_in[6];
  const float* W2    = (const float*)d_in[7];
  const float* b2    = (const float*)d_in[8];
  const float* Wf    = (const float*)d_in[9];
  const float* bfv   = (const float*)d_in[10];
  const float* gamma = (const float*)d_in[11];
  const float* beta  = (const float*)d_in[12];
  float* out = (float*)d_out;

  char* ws = (char*)d_ws;
  unsigned short* nbuf = (unsigned short*)(ws + O_N);
  unsigned short* Wt1  = (unsigned short*)(ws + O_WT1);
  unsigned short* Wt2  = (unsigned short*)(ws + O_WT2);
  unsigned short* Wft  = (unsigned short*)(ws + O_WFT);
  unsigned short* h1   = (unsigned short*)(ws + O_H1);
  unsigned short* abuf = (unsigned short*)(ws + O_A);

  // pack weights: W^T in bf16
  k_transpose_cast<<<dim3(HID / 32, HID / 32), dim3(32, 8), 0, stream>>>(W1, Wt1, HID, HID);
  k_transpose_cast<<<dim3(HID / 32, HID / 32), dim3(32, 8), 0, stream>>>(W2, Wt2, HID, HID);
  k_transpose_cast<<<dim3(CO / 32, HID / 32), dim3(32, 8), 0, stream>>>(Wf, Wft, HID, CO);

  // n = node_emb @ Wi + bi
  k_node<<<BB * NN, CB, 0, stream>>>(node, Wi, bi, nbuf);

  // trunk + final per chunk (chunk == batch b)
  for (int c = 0; c < 2; ++c) {
    k_gemm1<<<(CH / 64) * 8, 256, 0, stream>>>(edge, nbuf, eidx, Wt1, b1, h1, c * CH, c);
    k_gemm2<<<(CH / 128) * 8, 256, 0, stream>>>(h1, Wt2, b2, edge, nbuf, eidx, abuf, c * CH, c);
    k_final<<<CH / 64, 256, 0, stream>>>(abuf, Wft, bfv, gamma, beta, out + (size_t)c * CH * CO);
  }
}

// Round 5
// 609.915 us; speedup vs baseline: 1.1119x; 1.1119x over previous
//
#include <hip/hip_runtime.h>
#include <stdint.h>

#define BB    2
#define NN    1280
#define KK    48
#define CN    384
#define CE    128
#define CB    192
#define HID   512
#define CO    128
#define MM    (BB*NN*KK)   /* 122880 */
#define CH    (MM/2)       /* chunk rows: 61440 = exactly one batch b */

typedef __bf16 bf16x8 __attribute__((ext_vector_type(8)));
typedef float  f32x4  __attribute__((ext_vector_type(4)));
typedef unsigned short u16x8 __attribute__((ext_vector_type(8)));

__device__ __forceinline__ unsigned short f2bf(float f) {
  unsigned int i = __builtin_bit_cast(unsigned int, f);
  unsigned int r = (i + 0x7fffu + ((i >> 16) & 1u)) >> 16;
  return (unsigned short)r;
}
__device__ __forceinline__ float bf2f(unsigned short u) {
  unsigned int v = ((unsigned int)u) << 16;
  return __builtin_bit_cast(float, v);
}

// async global->LDS, 16B/lane; LDS dest is wave-uniform base + lane*16.
__device__ __forceinline__ void gload_lds16(const void* g, void* l) {
  __builtin_amdgcn_global_load_lds(
      (const __attribute__((address_space(1))) void*)g,
      (__attribute__((address_space(3))) void*)l, 16, 0, 0);
}

// ---------------- transpose+cast: out_bf16[C][R] = in_f32[R][C] ----------------
__global__ void k_transpose_cast(const float* __restrict__ in,
                                 unsigned short* __restrict__ out,
                                 int R, int C) {
  __shared__ float tile[32][33];
  const int c0 = blockIdx.x * 32, r0 = blockIdx.y * 32;
  const int tx = threadIdx.x, ty = threadIdx.y;
#pragma unroll
  for (int dy = 0; dy < 32; dy += 8)
    tile[ty + dy][tx] = in[(size_t)(r0 + ty + dy) * C + c0 + tx];
  __syncthreads();
#pragma unroll
  for (int dy = 0; dy < 32; dy += 8)
    out[(size_t)(c0 + ty + dy) * R + r0 + tx] = f2bf(tile[tx][ty + dy]);
}

// ---------------- node embed: n = node_emb @ Wi + bi ----------------
__global__ void k_node(const float* __restrict__ node,
                       const float* __restrict__ Wi,
                       const float* __restrict__ bi,
                       unsigned short* __restrict__ nbuf) {
  __shared__ float row[CN];
  const int blk = blockIdx.x;
  const float* src = node + (size_t)blk * CN;
  for (int c = threadIdx.x; c < CN; c += CB) row[c] = src[c];
  __syncthreads();
  const int t = threadIdx.x;
  float acc = bi[t];
#pragma unroll 8
  for (int c = 0; c < CN; ++c) acc += row[c] * Wi[(size_t)c * CB + t];
  nbuf[(size_t)blk * CB + t] = f2bf(acc);
}

// ---------------- edge f32 -> bf16 (chunk), into spare workspace --------------
__global__ void k_cast_edge(const float* __restrict__ in,
                            unsigned short* __restrict__ outb) {
  const size_t i = ((size_t)blockIdx.x * 256 + threadIdx.x) * 8;
  const float4* p = (const float4*)(in + i);
  float4 a = p[0], c = p[1];
  u16x8 pk;
  pk[0] = f2bf(a.x); pk[1] = f2bf(a.y); pk[2] = f2bf(a.z); pk[3] = f2bf(a.w);
  pk[4] = f2bf(c.x); pk[5] = f2bf(c.y); pk[6] = f2bf(c.z); pk[7] = f2bf(c.w);
  *(u16x8*)(outb + i) = pk;
}

// =======================================================================
// Persistent-B streaming GEMM: block stages its 64-col B panel (XOR-
// swizzled) into LDS ONCE, then loops over 8 m-tiles with A in registers
// (32 rows/wave = 128 VGPR), half-swap prefetch (alo/ahi reloaded for
// t+1 right after their last use at t).  Zero barriers in the m-loop:
// B is read-only; epilogue uses wave-private LDS scratch (same-wave DS
// ordering).  Issue order keeps prefetches in flight across all waits.
// Block mapping: work = (bid&7)*60 + (bid>>3) keeps the 8 n-panels of
// one m-panel on one XCD (assuming bid%8 -> XCD round-robin) so the A
// re-read is an L2 hit.  Performance heuristic only.
// =======================================================================

// ---------------- GEMM1: h1 = relu(x @ W1 + b1), x gathered to registers ----
// x[m] = [edge_bf16 (k<128) | nbuf[m/48] (128..320) | nbuf[b*N+eidx] (320..512)]
__global__ __launch_bounds__(256, 2)
void k_gemm1(const unsigned short* __restrict__ edgeb,  // [CH][128] bf16 chunk
             const unsigned short* __restrict__ nbuf,
             const int* __restrict__ eidx,
             const unsigned short* __restrict__ Wt,     // [512][512] = W1^T bf16
             const float* __restrict__ bias,
             unsigned short* __restrict__ out,          // h1 chunk [CH][512]
             int mbase, int b) {
  __shared__ char lds[81920];            // 64K B-panel + 4 x 4K wave scratch
  const int bid = blockIdx.x;            // 480 = 60 mg x 8 n
  const int work = (bid & 7) * 60 + (bid >> 3);
  const int mg = work >> 3;
  const int n0 = (work & 7) * 64;
  const int tid = threadIdx.x;
  const int l = tid & 63, w = tid >> 6;
  const int sr = l >> 3, pc = l & 7, lc = pc ^ sr;
  const int kg = l >> 4, lr = l & 15;

  // ---- B panel [8 win][64 rows][8 chunks], staged once ----
#pragma unroll
  for (int ww = 0; ww < 2; ++ww) {
    const int win = w * 2 + ww;
#pragma unroll
    for (int j = 0; j < 8; ++j)
      gload_lds16(Wt + (size_t)(n0 + j * 8 + sr) * HID + win * 64 + lc * 8,
                  lds + win * 8192 + j * 1024);
  }

  float bvv[4];
#pragma unroll
  for (int nt = 0; nt < 4; ++nt) bvv[nt] = bias[n0 + nt * 16 + lr];

  // ---- A(0) gather + eidx(1) ----
  bf16x8 alo[16], ahi[16];
  const int base0 = mg * 1024 + w * 32;
  int en0 = eidx[mbase + base0 + lr];
  int en1 = eidx[mbase + base0 + 16 + lr];
  {
    const int r0 = base0 + lr, r1 = base0 + 16 + lr;
    const int b0 = (mbase + r0) / KK, b1 = (mbase + r1) / KK;
    const int g0 = b * NN + en0, g1 = b * NN + en1;
#pragma unroll
    for (int s = 0; s < 4; ++s) {
      alo[s]     = *(const bf16x8*)(edgeb + (size_t)r0 * CE + s * 32 + kg * 8);
      alo[8 + s] = *(const bf16x8*)(edgeb + (size_t)r1 * CE + s * 32 + kg * 8);
    }
#pragma unroll
    for (int s = 4; s < 8; ++s) {
      alo[s]     = *(const bf16x8*)(nbuf + (size_t)b0 * CB + (s - 4) * 32 + kg * 8);
      alo[8 + s] = *(const bf16x8*)(nbuf + (size_t)b1 * CB + (s - 4) * 32 + kg * 8);
    }
#pragma unroll
    for (int s = 0; s < 2; ++s) {
      ahi[s]     = *(const bf16x8*)(nbuf + (size_t)b0 * CB + (s + 4) * 32 + kg * 8);
      ahi[8 + s] = *(const bf16x8*)(nbuf + (size_t)b1 * CB + (s + 4) * 32 + kg * 8);
    }
#pragma unroll
    for (int s = 2; s < 8; ++s) {
      ahi[s]     = *(const bf16x8*)(nbuf + (size_t)g0 * CB + (s - 2) * 32 + kg * 8);
      ahi[8 + s] = *(const bf16x8*)(nbuf + (size_t)g1 * CB + (s - 2) * 32 + kg * 8);
    }
  }
  en0 = eidx[mbase + base0 + 128 + lr];
  en1 = eidx[mbase + base0 + 128 + 16 + lr];
  __syncthreads();   // B visible; drains prologue (once)

  unsigned short* sw = (unsigned short*)(lds + 65536 + w * 4096);

  for (int t = 0; t < 8; ++t) {
    const int mloc = mg * 1024 + t * 128 + w * 32;
    const int tn = (t < 7) ? t + 1 : t;
    const int mnext = mg * 1024 + tn * 128 + w * 32;
    f32x4 acc[2][4];
#pragma unroll
    for (int mt = 0; mt < 2; ++mt)
#pragma unroll
      for (int nt = 0; nt < 4; ++nt) acc[mt][nt] = (f32x4){0.f, 0.f, 0.f, 0.f};

    // steps 0..7 (alo)
#pragma unroll
    for (int s = 0; s < 8; ++s) {
      const char* bwin = lds + (s >> 1) * 8192;
#pragma unroll
      for (int nt = 0; nt < 4; ++nt) {
        const int rb = nt * 16 + lr;
        const bf16x8 bv = *(const bf16x8*)(bwin + rb * 128 + ((((s & 1) << 2) + kg) ^ (rb & 7)) * 16);
        acc[0][nt] = __builtin_amdgcn_mfma_f32_16x16x32_bf16(alo[s], bv, acc[0][nt], 0, 0, 0);
        acc[1][nt] = __builtin_amdgcn_mfma_f32_16x16x32_bf16(alo[8 + s], bv, acc[1][nt], 0, 0, 0);
      }
    }
    // issue alo(t+1): edge + self (prefetch; younger than anything we wait on)
    {
      const int r0 = mnext + lr, r1 = mnext + 16 + lr;
      const int b0 = (mbase + r0) / KK, b1 = (mbase + r1) / KK;
#pragma unroll
      for (int s = 0; s < 4; ++s) {
        alo[s]     = *(const bf16x8*)(edgeb + (size_t)r0 * CE + s * 32 + kg * 8);
        alo[8 + s] = *(const bf16x8*)(edgeb + (size_t)r1 * CE + s * 32 + kg * 8);
      }
#pragma unroll
      for (int s = 4; s < 8; ++s) {
        alo[s]     = *(const bf16x8*)(nbuf + (size_t)b0 * CB + (s - 4) * 32 + kg * 8);
        alo[8 + s] = *(const bf16x8*)(nbuf + (size_t)b1 * CB + (s - 4) * 32 + kg * 8);
      }
      __builtin_amdgcn_sched_barrier(0);
      // steps 8..15 (ahi)
#pragma unroll
      for (int s = 0; s < 8; ++s) {
        const char* bwin = lds + (4 + (s >> 1)) * 8192;
#pragma unroll
        for (int nt = 0; nt < 4; ++nt) {
          const int rb = nt * 16 + lr;
          const bf16x8 bv = *(const bf16x8*)(bwin + rb * 128 + ((((s & 1) << 2) + kg) ^ (rb & 7)) * 16);
          acc[0][nt] = __builtin_amdgcn_mfma_f32_16x16x32_bf16(ahi[s], bv, acc[0][nt], 0, 0, 0);
          acc[1][nt] = __builtin_amdgcn_mfma_f32_16x16x32_bf16(ahi[8 + s], bv, acc[1][nt], 0, 0, 0);
        }
      }
      // issue ahi(t+1): self tail + nbr (consumes en0/en1), then eidx(t+2)
      const int g0 = b * NN + en0, g1 = b * NN + en1;
#pragma unroll
      for (int s = 0; s < 2; ++s) {
        ahi[s]     = *(const bf16x8*)(nbuf + (size_t)b0 * CB + (s + 4) * 32 + kg * 8);
        ahi[8 + s] = *(const bf16x8*)(nbuf + (size_t)b1 * CB + (s + 4) * 32 + kg * 8);
      }
#pragma unroll
      for (int s = 2; s < 8; ++s) {
        ahi[s]     = *(const bf16x8*)(nbuf + (size_t)g0 * CB + (s - 2) * 32 + kg * 8);
        ahi[8 + s] = *(const bf16x8*)(nbuf + (size_t)g1 * CB + (s - 2) * 32 + kg * 8);
      }
      const int tn2 = (t < 6) ? t + 2 : 7;
      const int mnn = mg * 1024 + tn2 * 128 + w * 32;
      en0 = eidx[mbase + mnn + lr];
      en1 = eidx[mbase + mnn + 16 + lr];
      __builtin_amdgcn_sched_barrier(0);
    }
    // epilogue: bias+relu -> wave scratch -> 16B stores (wave-private, no barrier)
#pragma unroll
    for (int mt = 0; mt < 2; ++mt)
#pragma unroll
      for (int nt = 0; nt < 4; ++nt) {
        const int col = nt * 16 + lr;
        const int cn = col >> 3, cb = col & 7;
#pragma unroll
        for (int r = 0; r < 4; ++r) {
          float v = acc[mt][nt][r] + bvv[nt];
          v = v > 0.f ? v : 0.f;
          const int row = mt * 16 + kg * 4 + r;
          sw[row * 64 + ((cn ^ (row & 7)) << 3) + cb] = f2bf(v);
        }
      }
#pragma unroll
    for (int j = 0; j < 4; ++j) {
      const int row = l >> 1, c = (l & 1) * 4 + j;
      u16x8 vv = *(const u16x8*)(sw + row * 64 + ((c ^ (row & 7)) << 3));
      *(u16x8*)(out + (size_t)(mloc + row) * HID + n0 + c * 8) = vv;
    }
  }
}

// ---------------- GEMM2: a = relu(h1 @ W2 + b2) + x (resid early-staged) -----
__global__ __launch_bounds__(256, 2)
void k_gemm2(const unsigned short* __restrict__ A,    // h1 chunk
             const unsigned short* __restrict__ Wt,   // W2^T bf16
             const float* __restrict__ bias,
             const float* __restrict__ edge,          // full f32 edge (resid)
             const unsigned short* __restrict__ nbuf,
             const int* __restrict__ eidx,
             unsigned short* __restrict__ out,        // abuf chunk
             int mbase, int b) {
  __shared__ char lds[81920];
  const int bid = blockIdx.x;            // 480 = 60 mg x 8 n
  const int work = (bid & 7) * 60 + (bid >> 3);
  const int mg = work >> 3;
  const int n0 = (work & 7) * 64;
  const int tid = threadIdx.x;
  const int l = tid & 63, w = tid >> 6;
  const int sr = l >> 3, pc = l & 7, lc = pc ^ sr;
  const int kg = l >> 4, lr = l & 15;

  // ---- B panel ----
#pragma unroll
  for (int ww = 0; ww < 2; ++ww) {
    const int win = w * 2 + ww;
#pragma unroll
    for (int j = 0; j < 8; ++j)
      gload_lds16(Wt + (size_t)(n0 + j * 8 + sr) * HID + win * 64 + lc * 8,
                  lds + win * 8192 + j * 1024);
  }

  float bvv[4];
#pragma unroll
  for (int nt = 0; nt < 4; ++nt) bvv[nt] = bias[n0 + nt * 16 + lr];

  // ---- A(0) ----
  bf16x8 alo[16], ahi[16];
  const int base0 = mg * 1024 + w * 32;
  {
    const unsigned short* a0 = A + (size_t)(base0 + lr) * HID + kg * 8;
    const unsigned short* a1 = A + (size_t)(base0 + 16 + lr) * HID + kg * 8;
#pragma unroll
    for (int s = 0; s < 8; ++s) { alo[s] = *(const bf16x8*)(a0 + s * 32); alo[8 + s] = *(const bf16x8*)(a1 + s * 32); }
#pragma unroll
    for (int s = 0; s < 8; ++s) { ahi[s] = *(const bf16x8*)(a0 + 256 + s * 32); ahi[8 + s] = *(const bf16x8*)(a1 + 256 + s * 32); }
  }
  __syncthreads();

  unsigned short* sw = (unsigned short*)(lds + 65536 + w * 4096);

  for (int t = 0; t < 8; ++t) {
    const int mloc = mg * 1024 + t * 128 + w * 32;
    const int tn = (t < 7) ? t + 1 : t;
    const int mnext = mg * 1024 + tn * 128 + w * 32;
    f32x4 acc[2][4];
#pragma unroll
    for (int mt = 0; mt < 2; ++mt)
#pragma unroll
      for (int nt = 0; nt < 4; ++nt) acc[mt][nt] = (f32x4){0.f, 0.f, 0.f, 0.f};

    // steps 0..7 (alo)
#pragma unroll
    for (int s = 0; s < 8; ++s) {
      const char* bwin = lds + (s >> 1) * 8192;
#pragma unroll
      for (int nt = 0; nt < 4; ++nt) {
        const int rb = nt * 16 + lr;
        const bf16x8 bv = *(const bf16x8*)(bwin + rb * 128 + ((((s & 1) << 2) + kg) ^ (rb & 7)) * 16);
        acc[0][nt] = __builtin_amdgcn_mfma_f32_16x16x32_bf16(alo[s], bv, acc[0][nt], 0, 0, 0);
        acc[1][nt] = __builtin_amdgcn_mfma_f32_16x16x32_bf16(alo[8 + s], bv, acc[1][nt], 0, 0, 0);
      }
    }
    // resid(t) early-issue into regs (OLDER than A(t+1) prefetch, so the
    // epilogue's consumption wait cannot drain the prefetch)
    const int rrow = mbase + mloc + (l >> 1);
    float4 rf[8];
    u16x8 rb16[4];
    if (n0 < 128) {
#pragma unroll
      for (int j = 0; j < 4; ++j) {
        const int c = (l & 1) * 4 + j;
        const float4* rp = (const float4*)(edge + (size_t)rrow * CE + n0 + c * 8);
        rf[j * 2] = rp[0];
        rf[j * 2 + 1] = rp[1];
      }
    } else if (n0 < 320) {
      const unsigned short* qp = nbuf + (size_t)(rrow / KK) * CB + (n0 - 128);
#pragma unroll
      for (int j = 0; j < 4; ++j) rb16[j] = *(const u16x8*)(qp + ((l & 1) * 4 + j) * 8);
    } else {
      const int e = eidx[rrow];
      const unsigned short* qp = nbuf + (size_t)(b * NN + e) * CB + (n0 - 320);
#pragma unroll
      for (int j = 0; j < 4; ++j) rb16[j] = *(const u16x8*)(qp + ((l & 1) * 4 + j) * 8);
    }
    __builtin_amdgcn_sched_barrier(0);
    // issue alo(t+1)
    {
      const unsigned short* a0 = A + (size_t)(mnext + lr) * HID + kg * 8;
      const unsigned short* a1 = A + (size_t)(mnext + 16 + lr) * HID + kg * 8;
#pragma unroll
      for (int s = 0; s < 8; ++s) { alo[s] = *(const bf16x8*)(a0 + s * 32); alo[8 + s] = *(const bf16x8*)(a1 + s * 32); }
      __builtin_amdgcn_sched_barrier(0);
      // steps 8..15 (ahi)
#pragma unroll
      for (int s = 0; s < 8; ++s) {
        const char* bwin = lds + (4 + (s >> 1)) * 8192;
#pragma unroll
        for (int nt = 0; nt < 4; ++nt) {
          const int rb = nt * 16 + lr;
          const bf16x8 bv = *(const bf16x8*)(bwin + rb * 128 + ((((s & 1) << 2) + kg) ^ (rb & 7)) * 16);
          acc[0][nt] = __builtin_amdgcn_mfma_f32_16x16x32_bf16(ahi[s], bv, acc[0][nt], 0, 0, 0);
          acc[1][nt] = __builtin_amdgcn_mfma_f32_16x16x32_bf16(ahi[8 + s], bv, acc[1][nt], 0, 0, 0);
        }
      }
      // issue ahi(t+1)
#pragma unroll
      for (int s = 0; s < 8; ++s) { ahi[s] = *(const bf16x8*)(a0 + 256 + s * 32); ahi[8 + s] = *(const bf16x8*)(a1 + 256 + s * 32); }
      __builtin_amdgcn_sched_barrier(0);
    }
    // epilogue: bias+relu -> wave scratch; stores add staged residual
#pragma unroll
    for (int mt = 0; mt < 2; ++mt)
#pragma unroll
      for (int nt = 0; nt < 4; ++nt) {
        const int col = nt * 16 + lr;
        const int cn = col >> 3, cb = col & 7;
#pragma unroll
        for (int r = 0; r < 4; ++r) {
          float v = acc[mt][nt][r] + bvv[nt];
          v = v > 0.f ? v : 0.f;
          const int row = mt * 16 + kg * 4 + r;
          sw[row * 64 + ((cn ^ (row & 7)) << 3) + cb] = f2bf(v);
        }
      }
#pragma unroll
    for (int j = 0; j < 4; ++j) {
      const int row = l >> 1, c = (l & 1) * 4 + j;
      u16x8 vv = *(const u16x8*)(sw + row * 64 + ((c ^ (row & 7)) << 3));
      float rv[8];
      if (n0 < 128) {
        rv[0] = rf[j * 2].x; rv[1] = rf[j * 2].y; rv[2] = rf[j * 2].z; rv[3] = rf[j * 2].w;
        rv[4] = rf[j * 2 + 1].x; rv[5] = rf[j * 2 + 1].y; rv[6] = rf[j * 2 + 1].z; rv[7] = rf[j * 2 + 1].w;
      } else {
#pragma unroll
        for (int q2 = 0; q2 < 8; ++q2) rv[q2] = bf2f(rb16[j][q2]);
      }
#pragma unroll
      for (int q2 = 0; q2 < 8; ++q2) vv[q2] = f2bf(bf2f(vv[q2]) + rv[q2]);
      *(u16x8*)(out + (size_t)(mloc + row) * HID + n0 + c * 8) = vv;
    }
  }
}

// ---------------- final GEMM + LayerNorm (persistent-B, 2 m-tiles) -----------
__global__ __launch_bounds__(256, 1)
void k_final(const unsigned short* __restrict__ A,     // abuf chunk [CH][512]
             const unsigned short* __restrict__ Wft,   // [128][512] = Wf^T bf16
             const float* __restrict__ bias,
             const float* __restrict__ gamma,
             const float* __restrict__ beta,
             float* __restrict__ out) {
  __shared__ char lds[131072];           // full Wf^T panel [8 win][128 rows][8 ch]
  const int m0 = blockIdx.x * 256;       // 240 blocks
  const int tid = threadIdx.x;
  const int l = tid & 63, w = tid >> 6;
  const int sr = l >> 3, pc = l & 7, lc = pc ^ sr;
  const int kg = l >> 4, lr = l & 15;

#pragma unroll
  for (int ww = 0; ww < 2; ++ww) {
    const int win = w * 2 + ww;
#pragma unroll
    for (int j = 0; j < 16; ++j)
      gload_lds16(Wft + (size_t)(j * 8 + sr) * HID + win * 64 + lc * 8,
                  lds + win * 16384 + j * 1024);
  }

  float gg[8], bb[8], bs[8];
#pragma unroll
  for (int j = 0; j < 8; ++j) {
    const int col = j * 16 + lr;
    gg[j] = gamma[col];
    bb[j] = beta[col];
    bs[j] = bias[col];
  }

  bf16x8 alo[16], ahi[16];
  {
    const unsigned short* a0 = A + (size_t)(m0 + w * 32 + lr) * HID + kg * 8;
    const unsigned short* a1 = A + (size_t)(m0 + w * 32 + 16 + lr) * HID + kg * 8;
#pragma unroll
    for (int s = 0; s < 8; ++s) { alo[s] = *(const bf16x8*)(a0 + s * 32); alo[8 + s] = *(const bf16x8*)(a1 + s * 32); }
#pragma unroll
    for (int s = 0; s < 8; ++s) { ahi[s] = *(const bf16x8*)(a0 + 256 + s * 32); ahi[8 + s] = *(const bf16x8*)(a1 + 256 + s * 32); }
  }
  __syncthreads();

  for (int t = 0; t < 2; ++t) {
    const int mrow = m0 + t * 128 + w * 32;
    const int mnext = m0 + ((t < 1) ? 128 : 128) + w * 32;  // tile-1 rows
    f32x4 acc[2][8];
#pragma unroll
    for (int mt = 0; mt < 2; ++mt)
#pragma unroll
      for (int nt = 0; nt < 8; ++nt) acc[mt][nt] = (f32x4){0.f, 0.f, 0.f, 0.f};

#pragma unroll
    for (int s = 0; s < 8; ++s) {
      const char* bwin = lds + (s >> 1) * 16384;
#pragma unroll
      for (int nt = 0; nt < 8; ++nt) {
        const int rb = nt * 16 + lr;
        const bf16x8 bv = *(const bf16x8*)(bwin + rb * 128 + ((((s & 1) << 2) + kg) ^ (rb & 7)) * 16);
        acc[0][nt] = __builtin_amdgcn_mfma_f32_16x16x32_bf16(alo[s], bv, acc[0][nt], 0, 0, 0);
        acc[1][nt] = __builtin_amdgcn_mfma_f32_16x16x32_bf16(alo[8 + s], bv, acc[1][nt], 0, 0, 0);
      }
    }
    if (t == 0) {   // prefetch tile-1 alo
      const unsigned short* a0 = A + (size_t)(mnext + lr) * HID + kg * 8;
      const unsigned short* a1 = A + (size_t)(mnext + 16 + lr) * HID + kg * 8;
#pragma unroll
      for (int s = 0; s < 8; ++s) { alo[s] = *(const bf16x8*)(a0 + s * 32); alo[8 + s] = *(const bf16x8*)(a1 + s * 32); }
      __builtin_amdgcn_sched_barrier(0);
    }
#pragma unroll
    for (int s = 0; s < 8; ++s) {
      const char* bwin = lds + (4 + (s >> 1)) * 16384;
#pragma unroll
      for (int nt = 0; nt < 8; ++nt) {
        const int rb = nt * 16 + lr;
        const bf16x8 bv = *(const bf16x8*)(bwin + rb * 128 + ((((s & 1) << 2) + kg) ^ (rb & 7)) * 16);
        acc[0][nt] = __builtin_amdgcn_mfma_f32_16x16x32_bf16(ahi[s], bv, acc[0][nt], 0, 0, 0);
        acc[1][nt] = __builtin_amdgcn_mfma_f32_16x16x32_bf16(ahi[8 + s], bv, acc[1][nt], 0, 0, 0);
      }
    }
    if (t == 0) {   // prefetch tile-1 ahi
      const unsigned short* a0 = A + (size_t)(mnext + lr) * HID + kg * 8;
      const unsigned short* a1 = A + (size_t)(mnext + 16 + lr) * HID + kg * 8;
#pragma unroll
      for (int s = 0; s < 8; ++s) { ahi[s] = *(const bf16x8*)(a0 + 256 + s * 32); ahi[8 + s] = *(const bf16x8*)(a1 + 256 + s * 32); }
      __builtin_amdgcn_sched_barrier(0);
    }

    // LayerNorm + store for this tile
#pragma unroll
    for (int mt = 0; mt < 2; ++mt)
#pragma unroll
      for (int r = 0; r < 4; ++r) {
        float s = 0.f, ss = 0.f;
#pragma unroll
        for (int j = 0; j < 8; ++j) {
          const float v = acc[mt][j][r] + bs[j];
          acc[mt][j][r] = v;
          s += v;
          ss += v * v;
        }
#pragma unroll
        for (int mk = 1; mk < 16; mk <<= 1) {
          s  += __shfl_xor(s, mk, 64);
          ss += __shfl_xor(ss, mk, 64);
        }
        const float mu = s * (1.f / 128.f);
        const float var = ss * (1.f / 128.f) - mu * mu;
        const float rstd = rsqrtf(var + 1e-5f);
        const int row = mrow + mt * 16 + kg * 4 + r;
#pragma unroll
        for (int j = 0; j < 8; ++j) {
          const float v = (acc[mt][j][r] - mu) * rstd * gg[j] + bb[j];
          out[(size_t)row * CO + j * 16 + lr] = v;
        }
      }
  }
}

// ---------------- workspace layout (bytes) ----------------
// nbuf 983K | Wt1 512K | Wt2 512K | Wft 128K | h1 chunk 63M | abuf chunk 63M
// (edge_bf16 chunk, 15.7M, lives in the abuf region: consumed by gemm1 before
//  gemm2 overwrites abuf; stream order serializes)
#define O_N    ((size_t)0)
#define O_WT1  ((size_t)0x100000)
#define O_WT2  (O_WT1 + (size_t)0x80000)
#define O_WFT  (O_WT2 + (size_t)0x80000)
#define O_H1   ((size_t)0x300000)
#define O_A    (O_H1 + (size_t)CH * HID * 2)

extern "C" void kernel_launch(void* const* d_in, const int* in_sizes, int n_in,
                              void* d_out, int out_size, void* d_ws, size_t ws_size,
                              hipStream_t stream) {
  const float* node  = (const float*)d_in[0];
  const float* edge  = (const float*)d_in[1];
  const int*   eidx  = (const int*)d_in[2];
  const float* Wi    = (const float*)d_in[3];
  const float* bi    = (const float*)d_in[4];
  const float* W1    = (const float*)d_in[5];
  const float* b1    = (const float*)d_in[6];
  const float* W2    = (const float*)d_in[7];
  const float* b2    = (const float*)d_in[8];
  const float* Wf    = (const float*)d_in[9];
  const float* bfv   = (const float*)d_in[10];
  const float* gamma = (const float*)d_in[11];
  const float* beta  = (const float*)d_in[12];
  float* out = (float*)d_out;

  char* ws = (char*)d_ws;
  unsigned short* nbuf = (unsigned short*)(ws + O_N);
  unsigned short* Wt1  = (unsigned short*)(ws + O_WT1);
  unsigned short* Wt2  = (unsigned short*)(ws + O_WT2);
  unsigned short* Wft  = (unsigned short*)(ws + O_WFT);
  unsigned short* h1   = (unsigned short*)(ws + O_H1);
  unsigned short* abuf = (unsigned short*)(ws + O_A);
  unsigned short* ebuf = abuf;   // edge_bf16 chunk staging (pre-gemm2)

  // pack weights: W^T in bf16
  k_transpose_cast<<<dim3(HID / 32, HID / 32), dim3(32, 8), 0, stream>>>(W1, Wt1, HID, HID);
  k_transpose_cast<<<dim3(HID / 32, HID / 32), dim3(32, 8), 0, stream>>>(W2, Wt2, HID, HID);
  k_transpose_cast<<<dim3(CO / 32, HID / 32), dim3(32, 8), 0, stream>>>(Wf, Wft, HID, CO);

  // n = node_emb @ Wi + bi
  k_node<<<BB * NN, CB, 0, stream>>>(node, Wi, bi, nbuf);

  // trunk + final per chunk (chunk == batch b)
  for (int c = 0; c < 2; ++c) {
    k_cast_edge<<<(CH * CE) / 2048, 256, 0, stream>>>(edge + (size_t)c * CH * CE, ebuf);
    k_gemm1<<<480, 256, 0, stream>>>(ebuf, nbuf, eidx, Wt1, b1, h1, c * CH, c);
    k_gemm2<<<480, 256, 0, stream>>>(h1, Wt2, b2, edge, nbuf, eidx, abuf, c * CH, c);
    k_final<<<240, 256, 0, stream>>>(abuf, Wft, bfv, gamma, beta, out + (size_t)c * CH * CO);
  }
}

// Round 6
// 417.256 us; speedup vs baseline: 1.6252x; 1.4617x over previous
//
#include <hip/hip_runtime.h>
#include <stdint.h>

#define BB    2
#define NN    1280
#define KK    48
#define CN    384
#define CE    128
#define CB    192
#define HID   512
#define CO    128
#define MM    (BB*NN*KK)   /* 122880 */
#define CH    (MM/2)       /* chunk rows: 61440 = exactly one batch b */

typedef __bf16 bf16x8 __attribute__((ext_vector_type(8)));
typedef float  f32x4  __attribute__((ext_vector_type(4)));
typedef unsigned short u16x8 __attribute__((ext_vector_type(8)));

__device__ __forceinline__ unsigned short f2bf(float f) {
  unsigned int i = __builtin_bit_cast(unsigned int, f);
  unsigned int r = (i + 0x7fffu + ((i >> 16) & 1u)) >> 16;
  return (unsigned short)r;
}
__device__ __forceinline__ float bf2f(unsigned short u) {
  unsigned int v = ((unsigned int)u) << 16;
  return __builtin_bit_cast(float, v);
}

// async global->LDS, 16B/lane; per-lane GLOBAL addresses are fine, LDS dest
// is wave-uniform base + lane*16 (we always use that exact layout).
__device__ __forceinline__ void gload_lds16(const void* g, void* l) {
  __builtin_amdgcn_global_load_lds(
      (const __attribute__((address_space(1))) void*)g,
      (__attribute__((address_space(3))) void*)l, 16, 0, 0);
}

// shared MFMA inner block: 2 k-steps of 4x4 16x16x32 tiles, XOR-swizzled LDS
__device__ __forceinline__ void mfma_tiles(const char* ldsA, const char* ldsB,
                                           int l, int wm, int wn,
                                           f32x4 (&acc)[4][4]) {
#pragma unroll
  for (int kk = 0; kk < 2; ++kk) {
    bf16x8 av[4], bv[4];
#pragma unroll
    for (int t = 0; t < 4; ++t) {
      const int ra = wm * 64 + t * 16 + (l & 15);
      const int ca = (kk * 4 + (l >> 4)) ^ (ra & 7);
      av[t] = *(const bf16x8*)(ldsA + ra * 128 + ca * 16);
      const int rb = wn * 64 + t * 16 + (l & 15);
      const int cb = (kk * 4 + (l >> 4)) ^ (rb & 7);
      bv[t] = *(const bf16x8*)(ldsB + rb * 128 + cb * 16);
    }
#pragma unroll
    for (int mt = 0; mt < 4; ++mt)
#pragma unroll
      for (int nt = 0; nt < 4; ++nt)
        acc[mt][nt] = __builtin_amdgcn_mfma_f32_16x16x32_bf16(av[mt], bv[nt], acc[mt][nt], 0, 0, 0);
  }
}

// ---------------- transpose+cast: out_bf16[C][R] = in_f32[R][C] ----------------
__global__ void k_transpose_cast(const float* __restrict__ in,
                                 unsigned short* __restrict__ out,
                                 int R, int C) {
  __shared__ float tile[32][33];
  const int c0 = blockIdx.x * 32, r0 = blockIdx.y * 32;
  const int tx = threadIdx.x, ty = threadIdx.y;
#pragma unroll
  for (int dy = 0; dy < 32; dy += 8)
    tile[ty + dy][tx] = in[(size_t)(r0 + ty + dy) * C + c0 + tx];
  __syncthreads();
#pragma unroll
  for (int dy = 0; dy < 32; dy += 8)
    out[(size_t)(c0 + ty + dy) * R + r0 + tx] = f2bf(tile[tx][ty + dy]);
}

// ---------------- node embed: n = node_emb @ Wi + bi  (f32 compute, bf16 out) --
__global__ void k_node(const float* __restrict__ node,
                       const float* __restrict__ Wi,
                       const float* __restrict__ bi,
                       unsigned short* __restrict__ nbuf) {
  __shared__ float row[CN];
  const int blk = blockIdx.x;
  const float* src = node + (size_t)blk * CN;
  for (int c = threadIdx.x; c < CN; c += CB) row[c] = src[c];
  __syncthreads();
  const int t = threadIdx.x;
  float acc = bi[t];
#pragma unroll 8
  for (int c = 0; c < CN; ++c) acc += row[c] * Wi[(size_t)c * CB + t];
  nbuf[(size_t)blk * CB + t] = f2bf(acc);
}

// ---------------- GEMM1: h1 = relu(x @ W1 + b1), x assembled in-staging -------
// x[m] = [edge f32->bf16 (k<128) | nbuf[m/48] (128<=k<320) | nbuf[b*N+eidx[m]] (k>=320)]
// No 64-col k-window straddles a region boundary.
__global__ __launch_bounds__(256, 2)
void k_gemm1(const float* __restrict__ edge,
             const unsigned short* __restrict__ nbuf,
             const int* __restrict__ eidx,
             const unsigned short* __restrict__ Wt,   // [512][512] = W1^T bf16
             const float* __restrict__ bias,
             unsigned short* __restrict__ out,        // h1 chunk [CH][512]
             int mbase, int b) {
  __shared__ char lds[32768];
  char* ldsA = lds;
  char* ldsB = lds + 16384;
  const int flat = blockIdx.x;
  const int xcd = flat & 7;
  const int p = flat >> 3;
  const int m0 = (xcd * 60 + (p >> 2)) * 128;
  const int n0 = (p & 3) * 128;
  const int tid = threadIdx.x;
  const int l = tid & 63;
  const int w = tid >> 6;
  const int wm = w >> 1, wn = w & 1;
  const int sr = l >> 3, pc = l & 7;
  const int lc = pc ^ sr;   // logical chunk landing at physical slot pc

  // per-staging-row globals (row r = (w*4+ii)*8+sr)
  int rr[4], big[4], nbrg[4];
  size_t mg[4];
#pragma unroll
  for (int ii = 0; ii < 4; ++ii) {
    const int r = (w * 4 + ii) * 8 + sr;
    rr[ii] = r;
    const int m = mbase + m0 + r;
    mg[ii] = (size_t)m;
    big[ii] = m / KK;
    nbrg[ii] = b * NN + eidx[m];
  }

  f32x4 acc[4][4];
#pragma unroll
  for (int i = 0; i < 4; ++i)
#pragma unroll
    for (int j = 0; j < 4; ++j) acc[i][j] = (f32x4){0.f, 0.f, 0.f, 0.f};

#pragma unroll
  for (int k0 = 0; k0 < HID; k0 += 64) {
    uint4 rga[4];
    if (k0 < 128) {   // edge phase: manual f32->bf16 convert into regs
#pragma unroll
      for (int ii = 0; ii < 4; ++ii) {
        const float4* ep = (const float4*)(edge + mg[ii] * CE + k0 + lc * 8);
        float4 x0 = ep[0], x1 = ep[1];
        u16x8 pk;
        pk[0] = f2bf(x0.x); pk[1] = f2bf(x0.y); pk[2] = f2bf(x0.z); pk[3] = f2bf(x0.w);
        pk[4] = f2bf(x1.x); pk[5] = f2bf(x1.y); pk[6] = f2bf(x1.z); pk[7] = f2bf(x1.w);
        rga[ii] = __builtin_bit_cast(uint4, pk);
      }
    }
    __syncthreads();
#pragma unroll
    for (int ii = 0; ii < 4; ++ii) {
      const int i = w * 4 + ii;
      gload_lds16(Wt + (size_t)(n0 + rr[ii]) * HID + k0 + lc * 8, ldsB + i * 1024);
      if (k0 < 128) {
        *(uint4*)(ldsA + i * 1024 + l * 16) = rga[ii];
      } else if (k0 < 320) {
        gload_lds16(nbuf + (size_t)big[ii] * CB + (k0 - 128) + lc * 8, ldsA + i * 1024);
      } else {
        gload_lds16(nbuf + (size_t)nbrg[ii] * CB + (k0 - 320) + lc * 8, ldsA + i * 1024);
      }
    }
    __syncthreads();
    mfma_tiles(ldsA, ldsB, l, wm, wn, acc);
  }

  // epilogue: bias+relu -> bf16 LDS tile -> 16B row-contiguous stores
  __syncthreads();
  unsigned short* tile = (unsigned short*)lds;
  const int q = l >> 4, cc = l & 15;
#pragma unroll
  for (int nt = 0; nt < 4; ++nt) {
    const int col = wn * 64 + nt * 16 + cc;
    const float bvv = bias[n0 + col];
    const int cn = col >> 3, cb = col & 7;
#pragma unroll
    for (int mt = 0; mt < 4; ++mt) {
      const int r0_ = wm * 64 + mt * 16 + q * 4;
#pragma unroll
      for (int r = 0; r < 4; ++r) {
        float v = acc[mt][nt][r] + bvv;
        v = v > 0.f ? v : 0.f;
        const int row = r0_ + r;
        tile[row * 128 + ((cn ^ (row & 7)) << 3) + cb] = f2bf(v);
      }
    }
  }
  __syncthreads();
#pragma unroll
  for (int i = 0; i < 8; ++i) {
    const int c = i * 256 + tid;
    const int row = c >> 4, cn = c & 15;
    u16x8 vv = *(const u16x8*)(tile + row * 128 + ((cn ^ (row & 7)) << 3));
    *(u16x8*)(out + (size_t)(m0 + row) * HID + n0 + cn * 8) = vv;
  }
}

// ---------------- GEMM2: a = relu(h1 @ W2 + b2) + x, x re-gathered in epilogue -
__global__ __launch_bounds__(256, 2)
void k_gemm2(const unsigned short* __restrict__ A,    // h1 chunk
             const unsigned short* __restrict__ Wt,   // W2^T bf16
             const float* __restrict__ bias,
             const float* __restrict__ edge,
             const unsigned short* __restrict__ nbuf,
             const int* __restrict__ eidx,
             unsigned short* __restrict__ out,        // abuf chunk
             int mbase, int b) {
  __shared__ char lds[32768];
  char* ldsA = lds;
  char* ldsB = lds + 16384;
  const int flat = blockIdx.x;
  const int xcd = flat & 7;
  const int p = flat >> 3;
  const int m0 = (xcd * 60 + (p >> 2)) * 128;
  const int n0 = (p & 3) * 128;
  const int tid = threadIdx.x;
  const int l = tid & 63;
  const int w = tid >> 6;
  const int wm = w >> 1, wn = w & 1;
  const int sr = l >> 3, pc = l & 7;
  const int lc = pc ^ sr;

  f32x4 acc[4][4];
#pragma unroll
  for (int i = 0; i < 4; ++i)
#pragma unroll
    for (int j = 0; j < 4; ++j) acc[i][j] = (f32x4){0.f, 0.f, 0.f, 0.f};

#pragma unroll
  for (int k0 = 0; k0 < HID; k0 += 64) {
    __syncthreads();
#pragma unroll
    for (int ii = 0; ii < 4; ++ii) {
      const int i = w * 4 + ii;
      const int r = i * 8 + sr;
      gload_lds16(A  + (size_t)(m0 + r) * HID + k0 + lc * 8, ldsA + i * 1024);
      gload_lds16(Wt + (size_t)(n0 + r) * HID + k0 + lc * 8, ldsB + i * 1024);
    }
    __syncthreads();
    mfma_tiles(ldsA, ldsB, l, wm, wn, acc);
  }

  // epilogue: bias+relu -> LDS tile; store loop re-gathers residual x
  __syncthreads();
  unsigned short* tile = (unsigned short*)lds;
  const int q = l >> 4, cc = l & 15;
#pragma unroll
  for (int nt = 0; nt < 4; ++nt) {
    const int col = wn * 64 + nt * 16 + cc;
    const float bvv = bias[n0 + col];
    const int cn = col >> 3, cb = col & 7;
#pragma unroll
    for (int mt = 0; mt < 4; ++mt) {
      const int r0_ = wm * 64 + mt * 16 + q * 4;
#pragma unroll
      for (int r = 0; r < 4; ++r) {
        float v = acc[mt][nt][r] + bvv;
        v = v > 0.f ? v : 0.f;
        const int row = r0_ + r;
        tile[row * 128 + ((cn ^ (row & 7)) << 3) + cb] = f2bf(v);
      }
    }
  }
  __syncthreads();
#pragma unroll
  for (int i = 0; i < 8; ++i) {
    const int c = i * 256 + tid;
    const int row = c >> 4, cn = c & 15;
    u16x8 vv = *(const u16x8*)(tile + row * 128 + ((cn ^ (row & 7)) << 3));
    const int m = mbase + m0 + row;
    float rv[8];
    if (n0 == 0) {                       // edge cols 0..127 (f32)
      const float4* ep = (const float4*)(edge + (size_t)m * CE + cn * 8);
      float4 x0 = ep[0], x1 = ep[1];
      rv[0] = x0.x; rv[1] = x0.y; rv[2] = x0.z; rv[3] = x0.w;
      rv[4] = x1.x; rv[5] = x1.y; rv[6] = x1.z; rv[7] = x1.w;
    } else if (n0 == 128) {              // self cols 128..255
      u16x8 xv = *(const u16x8*)(nbuf + (size_t)(m / KK) * CB + cn * 8);
#pragma unroll
      for (int j = 0; j < 8; ++j) rv[j] = bf2f(xv[j]);
    } else if (n0 == 256) {              // cols 256..383: self<320, nbr>=320
      u16x8 xv;
      if (cn < 8) {
        xv = *(const u16x8*)(nbuf + (size_t)(m / KK) * CB + 128 + cn * 8);
      } else {
        const int e = eidx[m];
        xv = *(const u16x8*)(nbuf + (size_t)(b * NN + e) * CB + cn * 8 - 64);
      }
#pragma unroll
      for (int j = 0; j < 8; ++j) rv[j] = bf2f(xv[j]);
    } else {                             // nbr cols 384..511
      const int e = eidx[m];
      u16x8 xv = *(const u16x8*)(nbuf + (size_t)(b * NN + e) * CB + 64 + cn * 8);
#pragma unroll
      for (int j = 0; j < 8; ++j) rv[j] = bf2f(xv[j]);
    }
#pragma unroll
    for (int j = 0; j < 8; ++j) vv[j] = f2bf(bf2f(vv[j]) + rv[j]);
    *(u16x8*)(out + (size_t)(m0 + row) * HID + n0 + cn * 8) = vv;
  }
}

// ---------------- final GEMM + LayerNorm: persistent-B in LDS, A in regs -----
// Wft (128x512 bf16 = 128KB) staged ONCE into LDS; each wave holds its 32 A-rows
// x K=512 in 128 VGPRs.  One __syncthreads, then a barrier-free 16-step K-loop
// (reg-A x LDS-B MFMA), LayerNorm epilogue as in the proven base kernel.
__global__ __launch_bounds__(256, 1)
void k_final(const unsigned short* __restrict__ A,     // abuf chunk [CH][512]
             const unsigned short* __restrict__ Wft,   // [128][512] = Wf^T bf16
             const float* __restrict__ bias,
             const float* __restrict__ gamma,
             const float* __restrict__ beta,
             float* __restrict__ out) {
  __shared__ char lds[131072];           // [8 win][128 rows][8 chunks x16B]
  const int m0 = blockIdx.x * 128;       // 480 blocks
  const int tid = threadIdx.x;
  const int l = tid & 63, w = tid >> 6;
  const int sr = l >> 3, pc = l & 7;
  const int lc = pc ^ sr;
  const int kg = l >> 4, lr = l & 15;

  // ---- stage full Wft panel (once) ----
#pragma unroll
  for (int ww = 0; ww < 2; ++ww) {
    const int win = w * 2 + ww;
#pragma unroll
    for (int j = 0; j < 16; ++j)
      gload_lds16(Wft + (size_t)(j * 8 + sr) * HID + win * 64 + lc * 8,
                  lds + win * 16384 + j * 1024);
  }

  // ---- A: wave's 32 rows, full K, to registers ----
  bf16x8 alo[16], ahi[16];
  {
    const unsigned short* a0 = A + (size_t)(m0 + w * 32 + lr) * HID + kg * 8;
    const unsigned short* a1 = A + (size_t)(m0 + w * 32 + 16 + lr) * HID + kg * 8;
#pragma unroll
    for (int s = 0; s < 16; ++s) {
      alo[s] = *(const bf16x8*)(a0 + s * 32);
      ahi[s] = *(const bf16x8*)(a1 + s * 32);
    }
  }

  float gg[8], bb[8], bs[8];
#pragma unroll
  for (int j = 0; j < 8; ++j) {
    const int col = j * 16 + lr;
    gg[j] = gamma[col];
    bb[j] = beta[col];
    bs[j] = bias[col];
  }
  __syncthreads();   // drains B-stage (and A loads); only barrier in the kernel

  f32x4 acc[2][8];
#pragma unroll
  for (int mt = 0; mt < 2; ++mt)
#pragma unroll
    for (int nt = 0; nt < 8; ++nt) acc[mt][nt] = (f32x4){0.f, 0.f, 0.f, 0.f};

#pragma unroll
  for (int s = 0; s < 16; ++s) {         // barrier-free K loop
    const char* bwin = lds + (s >> 1) * 16384;
#pragma unroll
    for (int nt = 0; nt < 8; ++nt) {
      const int rb = nt * 16 + lr;
      const bf16x8 bv = *(const bf16x8*)(bwin + rb * 128 + ((((s & 1) << 2) + kg) ^ (rb & 7)) * 16);
      acc[0][nt] = __builtin_amdgcn_mfma_f32_16x16x32_bf16(alo[s], bv, acc[0][nt], 0, 0, 0);
      acc[1][nt] = __builtin_amdgcn_mfma_f32_16x16x32_bf16(ahi[s], bv, acc[1][nt], 0, 0, 0);
    }
  }

  // ---- LayerNorm + store (proven reduction pattern: 16-lane shfl groups) ----
#pragma unroll
  for (int mt = 0; mt < 2; ++mt)
#pragma unroll
    for (int r = 0; r < 4; ++r) {
      float s = 0.f, ss = 0.f;
#pragma unroll
      for (int j = 0; j < 8; ++j) {
        const float v = acc[mt][j][r] + bs[j];
        acc[mt][j][r] = v;
        s += v;
        ss += v * v;
      }
#pragma unroll
      for (int mk = 1; mk < 16; mk <<= 1) {
        s  += __shfl_xor(s, mk, 64);
        ss += __shfl_xor(ss, mk, 64);
      }
      const float mu = s * (1.f / 128.f);
      const float var = ss * (1.f / 128.f) - mu * mu;
      const float rstd = rsqrtf(var + 1e-5f);
      const int row = m0 + w * 32 + mt * 16 + kg * 4 + r;
#pragma unroll
      for (int j = 0; j < 8; ++j) {
        const float v = (acc[mt][j][r] - mu) * rstd * gg[j] + bb[j];
        out[(size_t)row * CO + j * 16 + lr] = v;
      }
    }
}

// ---------------- workspace layout (bytes) ----------------
// nbuf 983K | Wt1 512K | Wt2 512K | Wft 128K | h1 chunk 63M | abuf chunk 63M
#define O_N    ((size_t)0)
#define O_WT1  ((size_t)0x100000)
#define O_WT2  (O_WT1 + (size_t)0x80000)
#define O_WFT  (O_WT2 + (size_t)0x80000)
#define O_H1   ((size_t)0x300000)
#define O_A    (O_H1 + (size_t)CH * HID * 2)

extern "C" void kernel_launch(void* const* d_in, const int* in_sizes, int n_in,
                              void* d_out, int out_size, void* d_ws, size_t ws_size,
                              hipStream_t stream) {
  const float* node  = (const float*)d_in[0];
  const float* edge  = (const float*)d_in[1];
  const int*   eidx  = (const int*)d_in[2];
  const float* Wi    = (const float*)d_in[3];
  const float* bi    = (const float*)d_in[4];
  const float* W1    = (const float*)d_in[5];
  const float* b1    = (const float*)d_in[6];
  const float* W2    = (const float*)d_in[7];
  const float* b2    = (const float*)d_in[8];
  const float* Wf    = (const float*)d_in[9];
  const float* bfv   = (const float*)d_in[10];
  const float* gamma = (const float*)d_in[11];
  const float* beta  = (const float*)d_in[12];
  float* out = (float*)d_out;

  char* ws = (char*)d_ws;
  unsigned short* nbuf = (unsigned short*)(ws + O_N);
  unsigned short* Wt1  = (unsigned short*)(ws + O_WT1);
  unsigned short* Wt2  = (unsigned short*)(ws + O_WT2);
  unsigned short* Wft  = (unsigned short*)(ws + O_WFT);
  unsigned short* h1   = (unsigned short*)(ws + O_H1);
  unsigned short* abuf = (unsigned short*)(ws + O_A);

  // pack weights: W^T in bf16
  k_transpose_cast<<<dim3(HID / 32, HID / 32), dim3(32, 8), 0, stream>>>(W1, Wt1, HID, HID);
  k_transpose_cast<<<dim3(HID / 32, HID / 32), dim3(32, 8), 0, stream>>>(W2, Wt2, HID, HID);
  k_transpose_cast<<<dim3(CO / 32, HID / 32), dim3(32, 8), 0, stream>>>(Wf, Wft, HID, CO);

  // n = node_emb @ Wi + bi
  k_node<<<BB * NN, CB, 0, stream>>>(node, Wi, bi, nbuf);

  // trunk + final per chunk (chunk == batch b)
  for (int c = 0; c < 2; ++c) {
    k_gemm1<<<(CH / 128) * 4, 256, 0, stream>>>(edge, nbuf, eidx, Wt1, b1, h1, c * CH, c);
    k_gemm2<<<(CH / 128) * 4, 256, 0, stream>>>(h1, Wt2, b2, edge, nbuf, eidx, abuf, c * CH, c);
    k_final<<<CH / 128, 256, 0, stream>>>(abuf, Wft, bfv, gamma, beta, out + (size_t)c * CH * CO);
  }
}